// Round 1
// baseline (741.021 us; speedup 1.0000x reference)
//
#include <hip/hip_runtime.h>

// NeuralIF GraphNet: 3 layers x (lower GraphNet, upper GraphNet).
// R1: bucketed edge lists + LDS-bin aggregation (no scattered global atomics).
// R4: no __threadfence / done-counter in hot kernels.
// R5: agg+node fused; inline global MLP in edge kernel wave 0.
// R6 FAILED: 4 edges/thread spilled in[4][18] to scratch (VGPR 84, 41ms dispatch).
// R7: edge kernel one-edge-per-thread (VGPR 28, full occupancy); parallel scan.
// R8 (this round): factorized edge MLP. 16 of 18 input rows of the edge MLP are
// per-NODE: precompute A[n][32] = sum_k x[n,k]*W1[8+k,:], B[n][32] = sum_k
// x[n,k]*W1[16+k,:] in a per-GraphNet nodew_kernel (100k nodes, ~51M FMA)
// instead of per-EDGE (1.1M edges, ~563M FMA). Edge kernel: gather A[row] +
// B[col] (2x128B, L3-resident fp32 tables) + eprev/skip FMA rows + ReLU + W2.
// ~250 VALU inst/thread vs ~730. Tables cost +25.6MB workspace.

typedef unsigned int u32;

#define NB_SHIFT 9
#define NB_SIZE 512
#define RSTRIDE 1104  // per-GraphNet region: ebins[64] nbins[64*16] pad

__device__ __forceinline__ float wave_sum(float v) {
#pragma unroll
    for (int off = 32; off > 0; off >>= 1) v += __shfl_down(v, off, 64);
    return v;
}

// ---------------- bucketed-list build (once per call) ----------------

__global__ __launch_bounds__(256) void hist_kernel(
    const int* __restrict__ lr, const int* __restrict__ ur,
    u32* __restrict__ hist, int E, int B) {
    __shared__ u32 h[256];
    const int t = threadIdx.x;
    if (t < B) h[t] = 0;
    __syncthreads();
    const int s = blockIdx.y;
    const int* rows = s ? ur : lr;
    for (int i = blockIdx.x * 256 + t; i < E; i += gridDim.x * 256)
        atomicAdd(&h[rows[i] >> NB_SHIFT], 1u);
    __syncthreads();
    if (t < B && h[t]) atomicAdd(&hist[s * B + t], h[t]);
}

// parallel exclusive scan of both segments (B <= 256), one block
__global__ __launch_bounds__(256) void scan_kernel(
    const u32* __restrict__ hist, u32* __restrict__ offs,
    u32* __restrict__ cur, int B) {
    __shared__ u32 sh[256];
    const int t = threadIdx.x;
    for (int s = 0; s < 2; ++s) {
        const u32 v = (t < B) ? hist[s * B + t] : 0u;
        sh[t] = v;
        __syncthreads();
#pragma unroll
        for (int off = 1; off < 256; off <<= 1) {
            const u32 add = (t >= off) ? sh[t - off] : 0u;
            __syncthreads();
            sh[t] += add;
            __syncthreads();
        }
        const u32 exc = sh[t] - v;
        if (t < B) {
            offs[s * (B + 1) + t] = exc;
            cur[s * B + t] = exc;
        }
        if (t == 255) offs[s * (B + 1) + B] = sh[255];
        __syncthreads();
    }
}

#define SCHUNK 4096
__global__ __launch_bounds__(256) void scatter_kernel(
    const int* __restrict__ lr, const int* __restrict__ ur,
    u32* __restrict__ cur, u32* __restrict__ list, int E, int B) {
    __shared__ u32 lcnt[256], lbase[256];
    const int t = threadIdx.x;
    const int s = blockIdx.y;
    const int* rows = s ? ur : lr;
    u32* mylist = list + (size_t)s * E;
    if (t < B) lcnt[t] = 0;
    __syncthreads();
    const int base_e = blockIdx.x * SCHUNK;
#pragma unroll
    for (int k = 0; k < SCHUNK / 256; ++k) {
        const int e = base_e + k * 256 + t;
        if (e < E) atomicAdd(&lcnt[rows[e] >> NB_SHIFT], 1u);
    }
    __syncthreads();
    if (t < B) {
        const u32 c = lcnt[t];
        lbase[t] = c ? atomicAdd(&cur[s * B + t], c) : 0u;
        lcnt[t] = 0;
    }
    __syncthreads();
#pragma unroll
    for (int k = 0; k < SCHUNK / 256; ++k) {
        const int e = base_e + k * 256 + t;
        if (e < E) {
            const int b = rows[e] >> NB_SHIFT;
            const u32 pos = lbase[b] + atomicAdd(&lcnt[b], 1u);
            mylist[pos] = (u32)e;
        }
    }
}

// -------- per-node W1 partial products (factorized edge MLP) --------
// A[n][j] = sum_k x[n,k] * W1[(8+k)*32+j]   (x[row] contribution)
// B[n][j] = sum_k x[n,k] * W1[(16+k)*32+j]  (x[col] contribution)

__global__ __launch_bounds__(256) void nodew_kernel(
    const float4* __restrict__ xf, const float* __restrict__ W1,
    float4* __restrict__ Atab, float4* __restrict__ Btab, int N) {
    const int n = blockIdx.x * 256 + threadIdx.x;
    if (n >= N) return;
    const float4 x0 = xf[2 * n], x1 = xf[2 * n + 1];
    const float xs[8] = {x0.x, x0.y, x0.z, x0.w, x1.x, x1.y, x1.z, x1.w};
    float a[32], b[32];
#pragma unroll
    for (int j = 0; j < 32; ++j) { a[j] = 0.0f; b[j] = 0.0f; }
    const float* __restrict__ WA = W1 + 8 * 32;
    const float* __restrict__ WB = W1 + 16 * 32;
#pragma unroll
    for (int k = 0; k < 8; ++k) {
        const float v = xs[k];
#pragma unroll
        for (int j = 0; j < 32; ++j) {
            a[j] = fmaf(v, WA[k * 32 + j], a[j]);
            b[j] = fmaf(v, WB[k * 32 + j], b[j]);
        }
    }
    float4* An = Atab + 8 * (size_t)n;
    float4* Bn = Btab + 8 * (size_t)n;
#pragma unroll
    for (int q = 0; q < 8; ++q) {
        An[q] = make_float4(a[4 * q], a[4 * q + 1], a[4 * q + 2], a[4 * q + 3]);
        Bn[q] = make_float4(b[4 * q], b[4 * q + 1], b[4 * q + 2], b[4 * q + 3]);
    }
}

// ---------------- edge MLP (+ inline global MLP in wave 0) ----------------
// One edge per thread. Factorized: h = biasE + A[row] + B[col]
//                                     + eprev*W1[24] + skip*W1[25].

template <bool SKIP, bool GAGG, bool VALS, bool STORE, bool GCOMP>
__global__ __launch_bounds__(256) void edge_kernel(
    const float4* __restrict__ Atab, const float4* __restrict__ Btab,
    const int* __restrict__ rows, const int* __restrict__ cols,
    const float* __restrict__ eprev,     // previous edge embedding (E)
    const float* __restrict__ skipattr,  // original attr (skip col), if SKIP
    const float* __restrict__ W1,        // 26x32 slice (row-major k,j)
    const float* __restrict__ b1,        // 32
    const float* __restrict__ W2,        // 32
    const float* __restrict__ b2,        // 1
    const float* __restrict__ gprev,     // gslot[j-1] (GCOMP) / gslot[0]=0
    float* __restrict__ gout,            // gslot[j] (GCOMP: block0 writes)
    const float* __restrict__ pebins,    // prev region e-mean bins (GCOMP)
    const float* __restrict__ pnbins,    // prev region n-mean bins (GCOMP)
    const float* __restrict__ gW1, const float* __restrict__ gb1,
    const float* __restrict__ gW2, const float* __restrict__ gb2,
    float* __restrict__ ebins,           // this region's e-mean bins (GAGG)
    float* __restrict__ e_out,           // edge emb store (STORE)
    float* __restrict__ vals_out,        // final output segment (VALS)
    int E, int N, float inv_E) {
    __shared__ float gsh[8];
    __shared__ float biasE[32];
    __shared__ float wpart[4];
    const int t = threadIdx.x;
    if constexpr (GCOMP) {
        if (t < 64) {  // wave 0: g = gMLP(n_mean, e_mean, g_prev)
            float nb[8];
#pragma unroll
            for (int q = 0; q < 8; ++q) nb[q] = pnbins[t * 16 + q];
            const float eb = pebins[t];
            float gin[17];
#pragma unroll
            for (int q = 0; q < 8; ++q) {
                const float s = wave_sum(nb[q]);
                gin[q] = __shfl(s, 0, 64) / (float)N;
            }
            const float es = wave_sum(eb);
            gin[8] = __shfl(es, 0, 64) * inv_E;
#pragma unroll
            for (int k = 0; k < 8; ++k) gin[9 + k] = gprev[k];
            float hv = 0.0f;
            if (t < 32) {
                hv = gb1[t];
#pragma unroll
                for (int k = 0; k < 17; ++k)
                    hv = fmaf(gin[k], gW1[k * 32 + t], hv);
                hv = fmaxf(hv, 0.0f);
            }
#pragma unroll
            for (int q = 0; q < 8; ++q) {
                const float c = (t < 32) ? hv * gW2[t * 8 + q] : 0.0f;
                const float s = wave_sum(c);
                if (t == 0) {
                    const float gv = gb2[q] + s;
                    gsh[q] = gv;
                    if (blockIdx.x == 0) gout[q] = gv;
                }
            }
        }
    } else {
        if (t < 8) gsh[t] = gprev[t];
    }
    __syncthreads();
    if (t < 32) {
        // fold uniform global contribution + b1 into per-pass bias
        float v = b1[t];
#pragma unroll
        for (int k = 0; k < 8; ++k) v = fmaf(gsh[k], W1[k * 32 + t], v);
        biasE[t] = v;
    }
    __syncthreads();

    const int e = blockIdx.x * 256 + t;
    const bool valid = e < E;
    const int idx = valid ? e : 0;
    const int r = rows[idx];
    const int c = cols[idx];
    const float ep = eprev[idx];
    float sk = 0.0f;
    if constexpr (SKIP) sk = skipattr[idx];
    const float4* __restrict__ Ar = Atab + 8 * (size_t)r;
    const float4* __restrict__ Bc = Btab + 8 * (size_t)c;
    const float* __restrict__ W24 = W1 + 24 * 32;
    const float* __restrict__ W25 = W1 + 25 * 32;
    float h[32];
#pragma unroll
    for (int q = 0; q < 8; ++q) {
        const float4 av = Ar[q];
        const float4 bv = Bc[q];
        const float4 bi = reinterpret_cast<const float4*>(biasE)[q];
        h[4 * q + 0] = bi.x + av.x + bv.x;
        h[4 * q + 1] = bi.y + av.y + bv.y;
        h[4 * q + 2] = bi.z + av.z + bv.z;
        h[4 * q + 3] = bi.w + av.w + bv.w;
    }
#pragma unroll
    for (int j = 0; j < 32; ++j) h[j] = fmaf(ep, W24[j], h[j]);
    if constexpr (SKIP) {
#pragma unroll
        for (int j = 0; j < 32; ++j) h[j] = fmaf(sk, W25[j], h[j]);
    }
    float out = b2[0];
#pragma unroll
    for (int j = 0; j < 32; ++j) out = fmaf(fmaxf(h[j], 0.0f), W2[j], out);

    if (valid) {
        if constexpr (STORE) e_out[e] = out;
        if constexpr (VALS) vals_out[e] = (r == c) ? expf(out) : out;
    }
    if constexpr (GAGG) {
        const float s = wave_sum(valid ? out : 0.0f);
        if ((t & 63) == 0) wpart[t >> 6] = s;
        __syncthreads();
        if (t == 0)
            atomicAdd(&ebins[blockIdx.x & 63],
                      wpart[0] + wpart[1] + wpart[2] + wpart[3]);
    }
}

// ------- fused aggregation + node MLP: one block owns one bucket -------

template <bool COUNT, bool STORE_N>
__global__ __launch_bounds__(1024) void aggnode_kernel(
    const u32* __restrict__ list, const u32* __restrict__ offs,
    const int* __restrict__ rows, const float* __restrict__ e_emb,
    const float4* __restrict__ xf,  // node features: x (lower) or l_n (upper)
    float* __restrict__ cntf,       // per-node degree (write if COUNT else read)
    const float* __restrict__ g,    // gslot[j] (materialized)
    const float* __restrict__ nW1, const float* __restrict__ nb1,
    const float* __restrict__ nW2, const float* __restrict__ nb2,
    float* __restrict__ n_out,  // l_n (8N) if STORE_N
    float* __restrict__ nbins,  // 64 x 16 n-mean partial bins
    int N) {
    __shared__ float sbin[NB_SIZE];
    __shared__ float cbin[NB_SIZE];
    __shared__ float biasN[32];
    __shared__ float npart[8][8];
    const int t = threadIdx.x;
    if (t < NB_SIZE) {
        sbin[t] = 0.0f;
        if constexpr (COUNT) cbin[t] = 0.0f;
    }
    if (t >= NB_SIZE && t < NB_SIZE + 32) {
        const int j = t - NB_SIZE;
        float v = nb1[j];
#pragma unroll
        for (int k = 0; k < 8; ++k) v = fmaf(g[k], nW1[k * 32 + j], v);
        biasN[j] = v;
    }
    __syncthreads();
    const int b = blockIdx.x;
    const u32 beg = offs[b], end = offs[b + 1];
    for (u32 i = beg + t; i < end; i += 1024) {
        const u32 eid = list[i];
        const float v = e_emb[eid];
        const int r = rows[eid];
        atomicAdd(&sbin[r & (NB_SIZE - 1)], v);
        if constexpr (COUNT) atomicAdd(&cbin[r & (NB_SIZE - 1)], 1.0f);
    }
    __syncthreads();

    const int n0 = b << NB_SHIFT;
    float o[8];
    const bool active = (t < NB_SIZE) && (n0 + t < N);
    if (t < NB_SIZE) {
        const int n = n0 + t;
        const int idx = active ? n : (N - 1);
        float cntv;
        if constexpr (COUNT) {
            cntv = cbin[t];
            if (active) cntf[n] = cntv;
        } else {
            cntv = cntf[idx];
        }
        const float agg = sbin[t] / fmaxf(cntv, 1.0f);
        const float4 x0 = xf[2 * idx], x1 = xf[2 * idx + 1];
        float in[9] = {x0.x, x0.y, x0.z, x0.w, x1.x, x1.y, x1.z, x1.w, agg};
        float h[32];
#pragma unroll
        for (int j = 0; j < 8; ++j) {
            const float4 bb = reinterpret_cast<const float4*>(biasN)[j];
            h[4 * j + 0] = bb.x; h[4 * j + 1] = bb.y;
            h[4 * j + 2] = bb.z; h[4 * j + 3] = bb.w;
        }
        const float* __restrict__ Wk = nW1 + 8 * 32;
#pragma unroll
        for (int k = 0; k < 9; ++k) {
            const float v = in[k];
#pragma unroll
            for (int j = 0; j < 32; ++j) h[j] = fmaf(v, Wk[k * 32 + j], h[j]);
        }
#pragma unroll
        for (int q = 0; q < 8; ++q) o[q] = nb2[q];
#pragma unroll
        for (int j = 0; j < 32; ++j) {
            const float hv = fmaxf(h[j], 0.0f);
#pragma unroll
            for (int q = 0; q < 8; ++q) o[q] = fmaf(hv, nW2[j * 8 + q], o[q]);
        }
        if constexpr (STORE_N) {
            if (active) {
                reinterpret_cast<float4*>(n_out)[2 * n] =
                    make_float4(o[0], o[1], o[2], o[3]);
                reinterpret_cast<float4*>(n_out)[2 * n + 1] =
                    make_float4(o[4], o[5], o[6], o[7]);
            }
        }
#pragma unroll
        for (int q = 0; q < 8; ++q) {
            const float s = wave_sum(active ? o[q] : 0.0f);
            if ((t & 63) == 0) npart[t >> 6][q] = s;
        }
    }
    __syncthreads();
    if (t < 8) {
        float a = 0.0f;
#pragma unroll
        for (int w = 0; w < 8; ++w) a += npart[w][t];
        atomicAdd(&nbins[(b & 63) * 16 + t], a);
    }
}

extern "C" void kernel_launch(void* const* d_in, const int* in_sizes, int n_in,
                              void* d_out, int out_size, void* d_ws,
                              size_t ws_size, hipStream_t stream) {
    const float* x = (const float*)d_in[0];
    const int* l_ei = (const int*)d_in[1];
    const int* u_ei = (const int*)d_in[2];
    const float* l_attr = (const float*)d_in[3];
    const float* u_attr = (const float*)d_in[4];
    const float* eW1 = (const float*)d_in[5];
    const float* eb1 = (const float*)d_in[6];
    const float* eW2 = (const float*)d_in[7];
    const float* eb2 = (const float*)d_in[8];
    const float* nW1 = (const float*)d_in[9];
    const float* nb1 = (const float*)d_in[10];
    const float* nW2 = (const float*)d_in[11];
    const float* nb2 = (const float*)d_in[12];
    const float* gW1 = (const float*)d_in[13];
    const float* gb1 = (const float*)d_in[14];
    const float* gW2 = (const float*)d_in[15];
    const float* gb2 = (const float*)d_in[16];

    const int E = in_sizes[3];      // 1,100,000
    const int N = in_sizes[0] / 8;  // 100,000
    const int B = (N + NB_SIZE - 1) >> NB_SHIFT;  // 196 buckets

    // workspace layout (floats). Tables first (16B-aligned at base).
    float* ws = (float*)d_ws;
    float* Atab = ws;                          // 32N
    float* Btab = Atab + (size_t)32 * N;       // 32N
    float* l_e = Btab + (size_t)32 * N;        // E
    float* u_e = l_e + E;                      // E
    float* l_n = u_e + E;                      // 8N (float4-aligned)
    float* cnt_l = l_n + (size_t)8 * N;        // N (float degree)
    float* cnt_u = cnt_l + N;                  // N
    float* gslot = cnt_u + N;                  // 7 x 8 (slot j = g used by GNet j)
    u32* hist = (u32*)(gslot + 56);            // 2B
    float* dyn_all = (float*)(hist + 2 * B);   // 5 * RSTRIDE
    u32* offs = (u32*)(dyn_all + 5 * RSTRIDE); // 2(B+1)
    u32* cur = offs + 2 * (B + 1);             // 2B
    u32* list = cur + 2 * B;                   // 2E (lower | upper)

    const int* lr = l_ei;
    const int* lc = l_ei + E;
    const int* ur = u_ei;
    const int* uc = u_ei + E;
    const int eg = (E + 255) / 256;
    const int ng = (N + 255) / 256;
    const int sg = (E + SCHUNK - 1) / SCHUNK;
    const float invE = 1.0f / (float)E;
    float* outL = (float*)d_out;
    float* outU = outL + E;
    const u32* offs_l = offs;
    const u32* offs_u = offs + (B + 1);
    const u32* list_l = list;
    const u32* list_u = list + E;

    // one memset: gslots + hist + all 5 bin regions
    hipMemsetAsync(gslot, 0, (size_t)(56 + 2 * B + 5 * RSTRIDE) * sizeof(float),
                   stream);
    hist_kernel<<<dim3(128, 2), 256, 0, stream>>>(lr, ur, hist, E, B);
    scan_kernel<<<1, 256, 0, stream>>>(hist, offs, cur, B);
    scatter_kernel<<<dim3(sg, 2), 256, 0, stream>>>(lr, ur, cur, list, E, B);

    // weight-slice per GraphNet j: lower i -> i, upper i -> 3+i
    const size_t wsl[6] = {0, 3, 1, 4, 2, 5};

    for (int j = 0; j < 6; ++j) {
        const bool lower = !(j & 1);
        const size_t sl = wsl[j];
        float* ebins = dyn_all + (size_t)(j <= 4 ? j : 4) * RSTRIDE;
        float* nbins = ebins + 64;
        const float* pe = (j >= 1) ? dyn_all + (size_t)(j - 1) * RSTRIDE : nullptr;
        const float* pn = (j >= 1) ? pe + 64 : nullptr;
        const size_t psl = (j >= 1) ? wsl[j - 1] : 0;
        const int* rows = lower ? lr : ur;
        const int* cols = lower ? lc : uc;
        const float* eprev = (j == 0) ? l_attr
                             : (j == 1) ? u_attr
                             : (lower ? l_e : u_e);
        float* e_out = lower ? l_e : u_e;
        const float* gprev = gslot + (size_t)(j >= 1 ? j - 1 : 0) * 8;
        float* gout = gslot + (size_t)j * 8;

        // per-node W1 partials for this GraphNet's edge MLP
        nodew_kernel<<<ng, 256, 0, stream>>>(
            (const float4*)(lower ? x : l_n), eW1 + sl * 832,
            (float4*)Atab, (float4*)Btab, N);

#define EDGE_ARGS                                                             \
    (const float4*)Atab, (const float4*)Btab, rows, cols, eprev, l_attr,      \
        eW1 + sl * 832, eb1 + sl * 32, eW2 + sl * 32, eb2 + sl, gprev, gout,  \
        pe, pn, gW1 + psl * 544, gb1 + psl * 32, gW2 + psl * 256,             \
        gb2 + psl * 8, ebins, e_out, (j == 4) ? outL : outU, E, N, invE

        switch (j) {  // SKIP, GAGG, VALS, STORE, GCOMP
            case 0: edge_kernel<false, true, false, true, false>
                        <<<eg, 256, 0, stream>>>(EDGE_ARGS); break;
            case 1: edge_kernel<false, true, false, true, true>
                        <<<eg, 256, 0, stream>>>(EDGE_ARGS); break;
            case 2: edge_kernel<true, true, false, true, true>
                        <<<eg, 256, 0, stream>>>(EDGE_ARGS); break;
            case 3: edge_kernel<false, true, false, true, true>
                        <<<eg, 256, 0, stream>>>(EDGE_ARGS); break;
            case 4: edge_kernel<true, true, true, true, true>
                        <<<eg, 256, 0, stream>>>(EDGE_ARGS); break;
            case 5: edge_kernel<false, false, true, false, true>
                        <<<eg, 256, 0, stream>>>(EDGE_ARGS); break;
        }
#undef EDGE_ARGS

        if (j == 5) break;  // final upper GraphNet: edge output only

        const u32* alist = lower ? list_l : list_u;
        const u32* aoffs = lower ? offs_l : offs_u;
        float* cntf = lower ? cnt_l : cnt_u;
        const float4* nxf = (const float4*)(lower ? x : l_n);

#define AGG_ARGS                                                              \
    alist, aoffs, rows, e_out, nxf, cntf, gslot + (size_t)j * 8,              \
        nW1 + sl * 544, nb1 + sl * 32, nW2 + sl * 256, nb2 + sl * 8, l_n,     \
        nbins, N

        switch (j) {  // COUNT, STORE_N
            case 0: aggnode_kernel<true, true>
                        <<<B, 1024, 0, stream>>>(AGG_ARGS); break;
            case 1: aggnode_kernel<true, false>
                        <<<B, 1024, 0, stream>>>(AGG_ARGS); break;
            case 2: aggnode_kernel<false, true>
                        <<<B, 1024, 0, stream>>>(AGG_ARGS); break;
            case 3: aggnode_kernel<false, false>
                        <<<B, 1024, 0, stream>>>(AGG_ARGS); break;
            case 4: aggnode_kernel<false, true>
                        <<<B, 1024, 0, stream>>>(AGG_ARGS); break;
        }
#undef AGG_ARGS
    }
}

// Round 2
// 674.610 us; speedup vs baseline: 1.0984x; 1.0984x over previous
//
#include <hip/hip_runtime.h>

// NeuralIF GraphNet: 3 layers x (lower GraphNet, upper GraphNet).
// R1: bucketed edge lists + LDS-bin aggregation (no scattered global atomics).
// R5: agg+node fused; inline global MLP in edge kernel wave 0.
// R7: one-edge-per-thread edge kernel (VGPR 28, full occupancy). 548us.
// R8 FAILED: A/B-table factorization with original edge order. Tables
// (12.8MB each) miss per-XCD L2 (4MB); random 128B gathers -> 139MB
// FETCH/dispatch at 2.26TB/s effective -> 67us/dispatch (was 49.5).
// R9 (this round): keep row-side factorization but process edges in
// BUCKET-PERMUTED order so A[row] gathers stay in a 64KB L1/L2-hot window.
// Col side recomputed from x[col] (32B gather, 3.2MB L2-resident) instead of
// B-table. Edge arrays (rowp/colp/attr/edge-emb) stored in permuted order ->
// all streaming accesses coalesced; aggnode reads become contiguous too.
// Only vals_out[list[i]] (final output, j=4,5) stays a scattered 4B write.

typedef unsigned int u32;

#define NB_SHIFT 9
#define NB_SIZE 512
#define RSTRIDE 1104  // per-GraphNet region: ebins[64] nbins[64*16] pad

__device__ __forceinline__ float wave_sum(float v) {
#pragma unroll
    for (int off = 32; off > 0; off >>= 1) v += __shfl_down(v, off, 64);
    return v;
}

// ---------------- bucketed-list build (once per call) ----------------

__global__ __launch_bounds__(256) void hist_kernel(
    const int* __restrict__ lr, const int* __restrict__ ur,
    u32* __restrict__ hist, int E, int B) {
    __shared__ u32 h[256];
    const int t = threadIdx.x;
    if (t < B) h[t] = 0;
    __syncthreads();
    const int s = blockIdx.y;
    const int* rows = s ? ur : lr;
    for (int i = blockIdx.x * 256 + t; i < E; i += gridDim.x * 256)
        atomicAdd(&h[rows[i] >> NB_SHIFT], 1u);
    __syncthreads();
    if (t < B && h[t]) atomicAdd(&hist[s * B + t], h[t]);
}

// parallel exclusive scan of both segments (B <= 256), one block
__global__ __launch_bounds__(256) void scan_kernel(
    const u32* __restrict__ hist, u32* __restrict__ offs,
    u32* __restrict__ cur, int B) {
    __shared__ u32 sh[256];
    const int t = threadIdx.x;
    for (int s = 0; s < 2; ++s) {
        const u32 v = (t < B) ? hist[s * B + t] : 0u;
        sh[t] = v;
        __syncthreads();
#pragma unroll
        for (int off = 1; off < 256; off <<= 1) {
            const u32 add = (t >= off) ? sh[t - off] : 0u;
            __syncthreads();
            sh[t] += add;
            __syncthreads();
        }
        const u32 exc = sh[t] - v;
        if (t < B) {
            offs[s * (B + 1) + t] = exc;
            cur[s * B + t] = exc;
        }
        if (t == 255) offs[s * (B + 1) + B] = sh[255];
        __syncthreads();
    }
}

// scatter: build permuted edge arrays (list/rowp/colp/attrp) in bucket order
#define SCHUNK 4096
__global__ __launch_bounds__(256) void scatter_kernel(
    const int* __restrict__ lr, const int* __restrict__ lc,
    const int* __restrict__ ur, const int* __restrict__ uc,
    const float* __restrict__ la, const float* __restrict__ ua,
    u32* __restrict__ cur, u32* __restrict__ list, u32* __restrict__ rowp,
    u32* __restrict__ colp, float* __restrict__ attrp, int E, int B,
    int Ep) {
    __shared__ u32 lcnt[256], lbase[256];
    const int t = threadIdx.x;
    const int s = blockIdx.y;
    const int* rows = s ? ur : lr;
    const int* cols = s ? uc : lc;
    const float* attr = s ? ua : la;
    const size_t so = (size_t)s * Ep;
    u32* mylist = list + so;
    u32* myrow = rowp + so;
    u32* mycol = colp + so;
    float* myattr = attrp + so;
    if (t < B) lcnt[t] = 0;
    __syncthreads();
    const int base_e = blockIdx.x * SCHUNK;
#pragma unroll
    for (int k = 0; k < SCHUNK / 256; ++k) {
        const int e = base_e + k * 256 + t;
        if (e < E) atomicAdd(&lcnt[rows[e] >> NB_SHIFT], 1u);
    }
    __syncthreads();
    if (t < B) {
        const u32 c = lcnt[t];
        lbase[t] = c ? atomicAdd(&cur[s * B + t], c) : 0u;
        lcnt[t] = 0;
    }
    __syncthreads();
#pragma unroll
    for (int k = 0; k < SCHUNK / 256; ++k) {
        const int e = base_e + k * 256 + t;
        if (e < E) {
            const int r = rows[e];
            const int b = r >> NB_SHIFT;
            const u32 pos = lbase[b] + atomicAdd(&lcnt[b], 1u);
            mylist[pos] = (u32)e;
            myrow[pos] = (u32)r;
            mycol[pos] = (u32)cols[e];
            myattr[pos] = attr[e];
        }
    }
}

// -------- per-node W1 row-side partials (factorized edge MLP) --------
// A[n][j] = sum_k x[n,k] * W1[(8+k)*32+j]   (x[row] contribution)

__global__ __launch_bounds__(256) void nodew_kernel(
    const float4* __restrict__ xf, const float* __restrict__ W1,
    float4* __restrict__ Atab, int N) {
    const int n = blockIdx.x * 256 + threadIdx.x;
    if (n >= N) return;
    const float4 x0 = xf[2 * n], x1 = xf[2 * n + 1];
    const float xs[8] = {x0.x, x0.y, x0.z, x0.w, x1.x, x1.y, x1.z, x1.w};
    float a[32];
#pragma unroll
    for (int j = 0; j < 32; ++j) a[j] = 0.0f;
    const float* __restrict__ WA = W1 + 8 * 32;
#pragma unroll
    for (int k = 0; k < 8; ++k) {
        const float v = xs[k];
#pragma unroll
        for (int j = 0; j < 32; ++j) a[j] = fmaf(v, WA[k * 32 + j], a[j]);
    }
    float4* An = Atab + 8 * (size_t)n;
#pragma unroll
    for (int q = 0; q < 8; ++q)
        An[q] = make_float4(a[4 * q], a[4 * q + 1], a[4 * q + 2], a[4 * q + 3]);
}

// ---------------- edge MLP (+ inline global MLP in wave 0) ----------------
// Bucket-permuted order: i indexes the permuted edge list. A[row] gathers hit
// a 64KB window (consecutive i share a 512-node bucket). Col contribution
// computed from x[col] (L2-resident 3.2MB). h = biasE + A[row] + colFMA
//                                             + eprev*W1[24] + skip*W1[25].

template <bool SKIP, bool GAGG, bool VALS, bool STORE, bool GCOMP>
__global__ __launch_bounds__(256) void edge_kernel(
    const float4* __restrict__ Atab,
    const float4* __restrict__ xf,       // current node features (x or l_n)
    const u32* __restrict__ rowp, const u32* __restrict__ colp,
    const u32* __restrict__ list,        // original edge id (VALS scatter)
    const float* __restrict__ eprev,     // previous edge embedding (permuted)
    const float* __restrict__ skipp,     // permuted skip attr, if SKIP
    const float* __restrict__ W1,        // 26x32 slice (row-major k,j)
    const float* __restrict__ b1,        // 32
    const float* __restrict__ W2,        // 32
    const float* __restrict__ b2,        // 1
    const float* __restrict__ gprev,     // gslot[j-1] (GCOMP) / gslot[0]=0
    float* __restrict__ gout,            // gslot[j] (GCOMP: block0 writes)
    const float* __restrict__ pebins,    // prev region e-mean bins (GCOMP)
    const float* __restrict__ pnbins,    // prev region n-mean bins (GCOMP)
    const float* __restrict__ gW1, const float* __restrict__ gb1,
    const float* __restrict__ gW2, const float* __restrict__ gb2,
    float* __restrict__ ebins,           // this region's e-mean bins (GAGG)
    float* __restrict__ e_out,           // edge emb store (permuted, STORE)
    float* __restrict__ vals_out,        // final output segment (VALS)
    int E, int N, float inv_E) {
    __shared__ float gsh[8];
    __shared__ float biasE[32];
    __shared__ float wpart[4];
    const int t = threadIdx.x;
    if constexpr (GCOMP) {
        if (t < 64) {  // wave 0: g = gMLP(n_mean, e_mean, g_prev)
            float nb[8];
#pragma unroll
            for (int q = 0; q < 8; ++q) nb[q] = pnbins[t * 16 + q];
            const float eb = pebins[t];
            float gin[17];
#pragma unroll
            for (int q = 0; q < 8; ++q) {
                const float s = wave_sum(nb[q]);
                gin[q] = __shfl(s, 0, 64) / (float)N;
            }
            const float es = wave_sum(eb);
            gin[8] = __shfl(es, 0, 64) * inv_E;
#pragma unroll
            for (int k = 0; k < 8; ++k) gin[9 + k] = gprev[k];
            float hv = 0.0f;
            if (t < 32) {
                hv = gb1[t];
#pragma unroll
                for (int k = 0; k < 17; ++k)
                    hv = fmaf(gin[k], gW1[k * 32 + t], hv);
                hv = fmaxf(hv, 0.0f);
            }
#pragma unroll
            for (int q = 0; q < 8; ++q) {
                const float c = (t < 32) ? hv * gW2[t * 8 + q] : 0.0f;
                const float s = wave_sum(c);
                if (t == 0) {
                    const float gv = gb2[q] + s;
                    gsh[q] = gv;
                    if (blockIdx.x == 0) gout[q] = gv;
                }
            }
        }
    } else {
        if (t < 8) gsh[t] = gprev[t];
    }
    __syncthreads();
    if (t < 32) {
        // fold uniform global contribution + b1 into per-pass bias
        float v = b1[t];
#pragma unroll
        for (int k = 0; k < 8; ++k) v = fmaf(gsh[k], W1[k * 32 + t], v);
        biasE[t] = v;
    }
    __syncthreads();

    const int i = blockIdx.x * 256 + t;
    const bool valid = i < E;
    const int idx = valid ? i : 0;
    const u32 r = rowp[idx];
    const u32 c = colp[idx];
    const float epv = eprev[idx];
    float sk = 0.0f;
    if constexpr (SKIP) sk = skipp[idx];
    // issue A-window gather early (8x16B, L1/L2-hot 64KB window)
    const float4* __restrict__ Ar = Atab + 8 * (size_t)r;
    float4 av[8];
#pragma unroll
    for (int q = 0; q < 8; ++q) av[q] = Ar[q];
    // col features (32B gather, L2-resident table)
    const float4 xc0 = xf[2 * (size_t)c], xc1 = xf[2 * (size_t)c + 1];
    const float cx[8] = {xc0.x, xc0.y, xc0.z, xc0.w,
                         xc1.x, xc1.y, xc1.z, xc1.w};
    float h[32];
#pragma unroll
    for (int q = 0; q < 8; ++q) {
        const float4 bi = reinterpret_cast<const float4*>(biasE)[q];
        h[4 * q + 0] = bi.x; h[4 * q + 1] = bi.y;
        h[4 * q + 2] = bi.z; h[4 * q + 3] = bi.w;
    }
    const float* __restrict__ Wc = W1 + 16 * 32;  // col rows 16..23
#pragma unroll
    for (int k = 0; k < 8; ++k) {
        const float v = cx[k];
#pragma unroll
        for (int j = 0; j < 32; ++j) h[j] = fmaf(v, Wc[k * 32 + j], h[j]);
    }
    const float* __restrict__ W24 = W1 + 24 * 32;
#pragma unroll
    for (int j = 0; j < 32; ++j) h[j] = fmaf(epv, W24[j], h[j]);
    if constexpr (SKIP) {
        const float* __restrict__ W25 = W1 + 25 * 32;
#pragma unroll
        for (int j = 0; j < 32; ++j) h[j] = fmaf(sk, W25[j], h[j]);
    }
#pragma unroll
    for (int q = 0; q < 8; ++q) {
        h[4 * q + 0] += av[q].x; h[4 * q + 1] += av[q].y;
        h[4 * q + 2] += av[q].z; h[4 * q + 3] += av[q].w;
    }
    float out = b2[0];
#pragma unroll
    for (int j = 0; j < 32; ++j) out = fmaf(fmaxf(h[j], 0.0f), W2[j], out);

    if (valid) {
        if constexpr (STORE) e_out[i] = out;
        if constexpr (VALS) {
            const u32 eid = list[idx];
            vals_out[eid] = (r == c) ? expf(out) : out;
        }
    }
    if constexpr (GAGG) {
        const float s = wave_sum(valid ? out : 0.0f);
        if ((t & 63) == 0) wpart[t >> 6] = s;
        __syncthreads();
        if (t == 0)
            atomicAdd(&ebins[blockIdx.x & 63],
                      wpart[0] + wpart[1] + wpart[2] + wpart[3]);
    }
}

// ------- fused aggregation + node MLP: one block owns one bucket -------
// Permuted layout: reads ep[i]/rowp[i] contiguously for this bucket's segment.

template <bool COUNT, bool STORE_N>
__global__ __launch_bounds__(1024) void aggnode_kernel(
    const float* __restrict__ ep,     // permuted edge embeddings
    const u32* __restrict__ rowp,     // permuted global rows
    const u32* __restrict__ offs,
    const float4* __restrict__ xf,  // node features: x (lower) or l_n (upper)
    float* __restrict__ cntf,       // per-node degree (write if COUNT else read)
    const float* __restrict__ g,    // gslot[j] (materialized)
    const float* __restrict__ nW1, const float* __restrict__ nb1,
    const float* __restrict__ nW2, const float* __restrict__ nb2,
    float* __restrict__ n_out,  // l_n (8N) if STORE_N
    float* __restrict__ nbins,  // 64 x 16 n-mean partial bins
    int N) {
    __shared__ float sbin[NB_SIZE];
    __shared__ float cbin[NB_SIZE];
    __shared__ float biasN[32];
    __shared__ float npart[8][8];
    const int t = threadIdx.x;
    if (t < NB_SIZE) {
        sbin[t] = 0.0f;
        if constexpr (COUNT) cbin[t] = 0.0f;
    }
    if (t >= NB_SIZE && t < NB_SIZE + 32) {
        const int j = t - NB_SIZE;
        float v = nb1[j];
#pragma unroll
        for (int k = 0; k < 8; ++k) v = fmaf(g[k], nW1[k * 32 + j], v);
        biasN[j] = v;
    }
    __syncthreads();
    const int b = blockIdx.x;
    const u32 beg = offs[b], end = offs[b + 1];
    for (u32 i = beg + t; i < end; i += 1024) {
        const float v = ep[i];
        const u32 rl = rowp[i] & (NB_SIZE - 1);
        atomicAdd(&sbin[rl], v);
        if constexpr (COUNT) atomicAdd(&cbin[rl], 1.0f);
    }
    __syncthreads();

    const int n0 = b << NB_SHIFT;
    float o[8];
    const bool active = (t < NB_SIZE) && (n0 + t < N);
    if (t < NB_SIZE) {
        const int n = n0 + t;
        const int idx = active ? n : (N - 1);
        float cntv;
        if constexpr (COUNT) {
            cntv = cbin[t];
            if (active) cntf[n] = cntv;
        } else {
            cntv = cntf[idx];
        }
        const float agg = sbin[t] / fmaxf(cntv, 1.0f);
        const float4 x0 = xf[2 * idx], x1 = xf[2 * idx + 1];
        float in[9] = {x0.x, x0.y, x0.z, x0.w, x1.x, x1.y, x1.z, x1.w, agg};
        float h[32];
#pragma unroll
        for (int j = 0; j < 8; ++j) {
            const float4 bb = reinterpret_cast<const float4*>(biasN)[j];
            h[4 * j + 0] = bb.x; h[4 * j + 1] = bb.y;
            h[4 * j + 2] = bb.z; h[4 * j + 3] = bb.w;
        }
        const float* __restrict__ Wk = nW1 + 8 * 32;
#pragma unroll
        for (int k = 0; k < 9; ++k) {
            const float v = in[k];
#pragma unroll
            for (int j = 0; j < 32; ++j) h[j] = fmaf(v, Wk[k * 32 + j], h[j]);
        }
#pragma unroll
        for (int q = 0; q < 8; ++q) o[q] = nb2[q];
#pragma unroll
        for (int j = 0; j < 32; ++j) {
            const float hv = fmaxf(h[j], 0.0f);
#pragma unroll
            for (int q = 0; q < 8; ++q) o[q] = fmaf(hv, nW2[j * 8 + q], o[q]);
        }
        if constexpr (STORE_N) {
            if (active) {
                reinterpret_cast<float4*>(n_out)[2 * n] =
                    make_float4(o[0], o[1], o[2], o[3]);
                reinterpret_cast<float4*>(n_out)[2 * n + 1] =
                    make_float4(o[4], o[5], o[6], o[7]);
            }
        }
#pragma unroll
        for (int q = 0; q < 8; ++q) {
            const float s = wave_sum(active ? o[q] : 0.0f);
            if ((t & 63) == 0) npart[t >> 6][q] = s;
        }
    }
    __syncthreads();
    if (t < 8) {
        float a = 0.0f;
#pragma unroll
        for (int w = 0; w < 8; ++w) a += npart[w][t];
        atomicAdd(&nbins[(b & 63) * 16 + t], a);
    }
}

extern "C" void kernel_launch(void* const* d_in, const int* in_sizes, int n_in,
                              void* d_out, int out_size, void* d_ws,
                              size_t ws_size, hipStream_t stream) {
    const float* x = (const float*)d_in[0];
    const int* l_ei = (const int*)d_in[1];
    const int* u_ei = (const int*)d_in[2];
    const float* l_attr = (const float*)d_in[3];
    const float* u_attr = (const float*)d_in[4];
    const float* eW1 = (const float*)d_in[5];
    const float* eb1 = (const float*)d_in[6];
    const float* eW2 = (const float*)d_in[7];
    const float* eb2 = (const float*)d_in[8];
    const float* nW1 = (const float*)d_in[9];
    const float* nb1 = (const float*)d_in[10];
    const float* nW2 = (const float*)d_in[11];
    const float* nb2 = (const float*)d_in[12];
    const float* gW1 = (const float*)d_in[13];
    const float* gb1 = (const float*)d_in[14];
    const float* gW2 = (const float*)d_in[15];
    const float* gb2 = (const float*)d_in[16];

    const int E = in_sizes[3];      // 1,100,000
    const int N = in_sizes[0] / 8;  // 100,000
    const int B = (N + NB_SIZE - 1) >> NB_SHIFT;  // 196 buckets
    const int Ep = (E + 3) & ~3;    // float4-safe stride

    // workspace layout (floats). Atab first (16B-aligned at base).
    float* ws = (float*)d_ws;
    float* Atab = ws;                          // 32N
    float* l_e = Atab + (size_t)32 * N;        // Ep (permuted edge emb, lower)
    float* u_e = l_e + Ep;                     // Ep (permuted edge emb, upper)
    float* l_n = u_e + Ep;                     // 8N (float4-aligned)
    float* cnt_l = l_n + (size_t)8 * N;        // N (float degree)
    float* cnt_u = cnt_l + N;                  // N
    float* gslot = cnt_u + N;                  // 7 x 8
    u32* hist = (u32*)(gslot + 56);            // 2B
    float* dyn_all = (float*)(hist + 2 * B);   // 5 * RSTRIDE
    u32* offs = (u32*)(dyn_all + 5 * RSTRIDE); // 2(B+1)
    u32* cur = offs + 2 * (B + 1);             // 2B
    u32* list = cur + 2 * B;                   // 2Ep (lower | upper)
    u32* rowp = list + (size_t)2 * Ep;         // 2Ep
    u32* colp = rowp + (size_t)2 * Ep;         // 2Ep
    float* attrp = (float*)(colp + (size_t)2 * Ep);  // 2Ep (la_p | ua_p)

    const int* lr = l_ei;
    const int* lc = l_ei + E;
    const int* ur = u_ei;
    const int* uc = u_ei + E;
    const int eg = (E + 255) / 256;
    const int ng = (N + 255) / 256;
    const int sg = (E + SCHUNK - 1) / SCHUNK;
    const float invE = 1.0f / (float)E;
    float* outL = (float*)d_out;
    float* outU = outL + E;
    const u32* offs_l = offs;
    const u32* offs_u = offs + (B + 1);
    const float* la_p = attrp;
    const float* ua_p = attrp + Ep;

    // one memset: gslots + hist + all 5 bin regions
    hipMemsetAsync(gslot, 0, (size_t)(56 + 2 * B + 5 * RSTRIDE) * sizeof(float),
                   stream);
    hist_kernel<<<dim3(128, 2), 256, 0, stream>>>(lr, ur, hist, E, B);
    scan_kernel<<<1, 256, 0, stream>>>(hist, offs, cur, B);
    scatter_kernel<<<dim3(sg, 2), 256, 0, stream>>>(
        lr, lc, ur, uc, l_attr, u_attr, cur, list, rowp, colp, attrp, E, B, Ep);

    // weight-slice per GraphNet j: lower i -> i, upper i -> 3+i
    const size_t wsl[6] = {0, 3, 1, 4, 2, 5};

    for (int j = 0; j < 6; ++j) {
        const bool lower = !(j & 1);
        const size_t so = (size_t)(lower ? 0 : 1) * Ep;
        const size_t sl = wsl[j];
        float* ebins = dyn_all + (size_t)(j <= 4 ? j : 4) * RSTRIDE;
        float* nbins = ebins + 64;
        const float* pe = (j >= 1) ? dyn_all + (size_t)(j - 1) * RSTRIDE : nullptr;
        const float* pn = (j >= 1) ? pe + 64 : nullptr;
        const size_t psl = (j >= 1) ? wsl[j - 1] : 0;
        const float4* exf = (const float4*)(lower ? x : l_n);
        const u32* rowp_t = rowp + so;
        const u32* colp_t = colp + so;
        const u32* list_t = list + so;
        const float* eprev = (j == 0) ? la_p
                             : (j == 1) ? ua_p
                             : (lower ? l_e : u_e);
        float* e_out = lower ? l_e : u_e;
        const float* gprev = gslot + (size_t)(j >= 1 ? j - 1 : 0) * 8;
        float* gout = gslot + (size_t)j * 8;

        // per-node row-side W1 partials for this GraphNet's edge MLP
        nodew_kernel<<<ng, 256, 0, stream>>>(exf, eW1 + sl * 832,
                                             (float4*)Atab, N);

#define EDGE_ARGS                                                             \
    (const float4*)Atab, exf, rowp_t, colp_t, list_t, eprev, la_p,            \
        eW1 + sl * 832, eb1 + sl * 32, eW2 + sl * 32, eb2 + sl, gprev, gout,  \
        pe, pn, gW1 + psl * 544, gb1 + psl * 32, gW2 + psl * 256,             \
        gb2 + psl * 8, ebins, e_out, (j == 4) ? outL : outU, E, N, invE

        switch (j) {  // SKIP, GAGG, VALS, STORE, GCOMP
            case 0: edge_kernel<false, true, false, true, false>
                        <<<eg, 256, 0, stream>>>(EDGE_ARGS); break;
            case 1: edge_kernel<false, true, false, true, true>
                        <<<eg, 256, 0, stream>>>(EDGE_ARGS); break;
            case 2: edge_kernel<true, true, false, true, true>
                        <<<eg, 256, 0, stream>>>(EDGE_ARGS); break;
            case 3: edge_kernel<false, true, false, true, true>
                        <<<eg, 256, 0, stream>>>(EDGE_ARGS); break;
            case 4: edge_kernel<true, true, true, true, true>
                        <<<eg, 256, 0, stream>>>(EDGE_ARGS); break;
            case 5: edge_kernel<false, false, true, false, true>
                        <<<eg, 256, 0, stream>>>(EDGE_ARGS); break;
        }
#undef EDGE_ARGS

        if (j == 5) break;  // final upper GraphNet: edge output only

        const u32* aoffs = lower ? offs_l : offs_u;
        float* cntf = lower ? cnt_l : cnt_u;
        const float4* nxf = (const float4*)(lower ? x : l_n);

#define AGG_ARGS                                                              \
    e_out, rowp_t, aoffs, nxf, cntf, gslot + (size_t)j * 8, nW1 + sl * 544,   \
        nb1 + sl * 32, nW2 + sl * 256, nb2 + sl * 8, l_n, nbins, N

        switch (j) {  // COUNT, STORE_N
            case 0: aggnode_kernel<true, true>
                        <<<B, 1024, 0, stream>>>(AGG_ARGS); break;
            case 1: aggnode_kernel<true, false>
                        <<<B, 1024, 0, stream>>>(AGG_ARGS); break;
            case 2: aggnode_kernel<false, true>
                        <<<B, 1024, 0, stream>>>(AGG_ARGS); break;
            case 3: aggnode_kernel<false, false>
                        <<<B, 1024, 0, stream>>>(AGG_ARGS); break;
            case 4: aggnode_kernel<false, true>
                        <<<B, 1024, 0, stream>>>(AGG_ARGS); break;
        }
#undef AGG_ARGS
    }
}

// Round 3
// 606.440 us; speedup vs baseline: 1.2219x; 1.1124x over previous
//
#include <hip/hip_runtime.h>

// NeuralIF GraphNet: 3 layers x (lower GraphNet, upper GraphNet).
// R1: bucketed edge lists + LDS-bin aggregation.
// R7: one-edge-per-thread edge kernel. 548us.
// R8 FAILED: global A/B tables, original order -> 139MB L3 gather traffic.
// R9: bucket-permuted edge order + row-side A-table. Edge kernels off top-5,
//     but 4-array scattered scatter_kernel became 120us (WRITE_SIZE 160MB,
//     4.5x write amplification from four separate 4B scattered streams).
// R10 (this round):
//  (a) scatter packs {row,col,eid,attr} into ONE uint4 -> one 16B scattered
//      store per edge (clustered within buckets -> mostly full lines).
//  (b) edge kernel is now per-bucket (2 half-chunks/bucket, 512 thr): computes
//      the bucket's 512-node W1-partial window (bias folded) directly into a
//      64KB LDS window (XOR-swizzled, T2) - no global Atab, no nodew kernel,
//      A reads are 8x ds_read_b128 instead of 128B L2 gathers.
//  (c) einfo.w doubles as eprev (j=0,1) / skip attr (j=2,4); aggnode reads
//      bucket-local row from einfo[i].x (coalesced).

typedef unsigned int u32;

#define NB_SHIFT 9
#define NB_SIZE 512
#define RSTRIDE 1104  // per-GraphNet region: ebins[64] nbins[64*16] pad

__device__ __forceinline__ float wave_sum(float v) {
#pragma unroll
    for (int off = 32; off > 0; off >>= 1) v += __shfl_down(v, off, 64);
    return v;
}

// ---------------- bucketed-list build (once per call) ----------------

__global__ __launch_bounds__(256) void hist_kernel(
    const int* __restrict__ lr, const int* __restrict__ ur,
    u32* __restrict__ hist, int E, int B) {
    __shared__ u32 h[256];
    const int t = threadIdx.x;
    if (t < B) h[t] = 0;
    __syncthreads();
    const int s = blockIdx.y;
    const int* rows = s ? ur : lr;
    for (int i = blockIdx.x * 256 + t; i < E; i += gridDim.x * 256)
        atomicAdd(&h[rows[i] >> NB_SHIFT], 1u);
    __syncthreads();
    if (t < B && h[t]) atomicAdd(&hist[s * B + t], h[t]);
}

// parallel exclusive scan of both segments (B <= 256), one block
__global__ __launch_bounds__(256) void scan_kernel(
    const u32* __restrict__ hist, u32* __restrict__ offs,
    u32* __restrict__ cur, int B) {
    __shared__ u32 sh[256];
    const int t = threadIdx.x;
    for (int s = 0; s < 2; ++s) {
        const u32 v = (t < B) ? hist[s * B + t] : 0u;
        sh[t] = v;
        __syncthreads();
#pragma unroll
        for (int off = 1; off < 256; off <<= 1) {
            const u32 add = (t >= off) ? sh[t - off] : 0u;
            __syncthreads();
            sh[t] += add;
            __syncthreads();
        }
        const u32 exc = sh[t] - v;
        if (t < B) {
            offs[s * (B + 1) + t] = exc;
            cur[s * B + t] = exc;
        }
        if (t == 255) offs[s * (B + 1) + B] = sh[255];
        __syncthreads();
    }
}

// scatter: build packed permuted edge records {row, col, eid, attr}
#define SCHUNK 4096
__global__ __launch_bounds__(256) void scatter_kernel(
    const int* __restrict__ lr, const int* __restrict__ lc,
    const int* __restrict__ ur, const int* __restrict__ uc,
    const float* __restrict__ la, const float* __restrict__ ua,
    u32* __restrict__ cur, uint4* __restrict__ einfo, int E, int B) {
    __shared__ u32 lcnt[256], lbase[256];
    const int t = threadIdx.x;
    const int s = blockIdx.y;
    const int* rows = s ? ur : lr;
    const int* cols = s ? uc : lc;
    const float* attr = s ? ua : la;
    uint4* my = einfo + (size_t)s * E;
    if (t < B) lcnt[t] = 0;
    __syncthreads();
    const int base_e = blockIdx.x * SCHUNK;
#pragma unroll
    for (int k = 0; k < SCHUNK / 256; ++k) {
        const int e = base_e + k * 256 + t;
        if (e < E) atomicAdd(&lcnt[rows[e] >> NB_SHIFT], 1u);
    }
    __syncthreads();
    if (t < B) {
        const u32 c = lcnt[t];
        lbase[t] = c ? atomicAdd(&cur[s * B + t], c) : 0u;
        lcnt[t] = 0;
    }
    __syncthreads();
#pragma unroll
    for (int k = 0; k < SCHUNK / 256; ++k) {
        const int e = base_e + k * 256 + t;
        if (e < E) {
            const int r = rows[e];
            const int b = r >> NB_SHIFT;
            const u32 pos = lbase[b] + atomicAdd(&lcnt[b], 1u);
            my[pos] = make_uint4((u32)r, (u32)cols[e], (u32)e,
                                 __float_as_uint(attr[e]));
        }
    }
}

// ---------------- edge MLP, per-bucket blocks ----------------
// Block = one half of one bucket's permuted edge segment. The bucket's
// 512-node row-side W1-partial window (bias + global term folded in) is
// computed into a 64KB XOR-swizzled LDS window, then edges read it via
// ds_read_b128. Col side recomputed from xf[col] (L2-resident).

template <bool SKIP, bool FIRST, bool GAGG, bool VALS, bool STORE, bool GCOMP>
__global__ __launch_bounds__(512) void edge_kernel(
    const uint4* __restrict__ einfo,     // packed permuted records
    const float4* __restrict__ xf,       // current node features (x or l_n)
    const u32* __restrict__ offs,        // bucket offsets (this segment)
    const float* __restrict__ eprev,     // prev edge emb (permuted), !FIRST
    const float* __restrict__ W1,        // 26x32 slice (row-major k,j)
    const float* __restrict__ b1,        // 32
    const float* __restrict__ W2,        // 32
    const float* __restrict__ b2,        // 1
    const float* __restrict__ gprev,     // gslot[j-1] (or gslot[0]=0)
    float* __restrict__ gout,            // gslot[j] (GCOMP: block0 writes)
    const float* __restrict__ pebins,    // prev region e-mean bins (GCOMP)
    const float* __restrict__ pnbins,    // prev region n-mean bins (GCOMP)
    const float* __restrict__ gW1, const float* __restrict__ gb1,
    const float* __restrict__ gW2, const float* __restrict__ gb2,
    float* __restrict__ ebins,           // this region's e-mean bins (GAGG)
    float* __restrict__ e_out,           // edge emb store (permuted, STORE)
    float* __restrict__ vals_out,        // final output segment (VALS)
    int N, float inv_E) {
    __shared__ float asw[NB_SIZE * 32];  // 64KB: swizzled A-window (reused)
    const int t = threadIdx.x;
    const int b = blockIdx.x >> 1;

    // ---- phase 0: global vector g -> asw[0..7] (temporary) ----
    if constexpr (GCOMP) {
        if (t < 64) {
            float nb[8];
#pragma unroll
            for (int q = 0; q < 8; ++q) nb[q] = pnbins[t * 16 + q];
            const float eb = pebins[t];
            float gin[17];
#pragma unroll
            for (int q = 0; q < 8; ++q) {
                const float s = wave_sum(nb[q]);
                gin[q] = __shfl(s, 0, 64) / (float)N;
            }
            const float es = wave_sum(eb);
            gin[8] = __shfl(es, 0, 64) * inv_E;
#pragma unroll
            for (int k = 0; k < 8; ++k) gin[9 + k] = gprev[k];
            float hv = 0.0f;
            if (t < 32) {
                hv = gb1[t];
#pragma unroll
                for (int k = 0; k < 17; ++k)
                    hv = fmaf(gin[k], gW1[k * 32 + t], hv);
                hv = fmaxf(hv, 0.0f);
            }
#pragma unroll
            for (int q = 0; q < 8; ++q) {
                const float c = (t < 32) ? hv * gW2[t * 8 + q] : 0.0f;
                const float s = wave_sum(c);
                if (t == 0) {
                    const float gv = gb2[q] + s;
                    asw[q] = gv;
                    if (blockIdx.x == 0) gout[q] = gv;
                }
            }
        }
    } else {
        if (t < 8) asw[t] = gprev[t];
    }
    __syncthreads();
    float gr[8];
#pragma unroll
    for (int k = 0; k < 8; ++k) gr[k] = asw[k];
    __syncthreads();  // before overwriting asw with the A-window

    // ---- phase 1: A-window: a[j] = b1[j] + g.W1[0:8] + x[n].W1[8:16] ----
    const int n = (b << NB_SHIFT) + t;
    if (n < N) {
        const float4 x0 = xf[2 * (size_t)n], x1 = xf[2 * (size_t)n + 1];
        const float xs[8] = {x0.x, x0.y, x0.z, x0.w, x1.x, x1.y, x1.z, x1.w};
        float a[32];
#pragma unroll
        for (int j = 0; j < 32; ++j) {
            float v = b1[j];
#pragma unroll
            for (int k = 0; k < 8; ++k) v = fmaf(gr[k], W1[k * 32 + j], v);
            a[j] = v;
        }
        const float* __restrict__ WA = W1 + 8 * 32;
#pragma unroll
        for (int k = 0; k < 8; ++k) {
            const float v = xs[k];
#pragma unroll
            for (int j = 0; j < 32; ++j) a[j] = fmaf(v, WA[k * 32 + j], a[j]);
        }
        const int base = t * 32;
        const int sw = (t & 7) << 2;
#pragma unroll
        for (int q = 0; q < 8; ++q) {
            *(float4*)&asw[base + ((q * 4) ^ sw)] =
                make_float4(a[4 * q], a[4 * q + 1], a[4 * q + 2], a[4 * q + 3]);
        }
    }
    __syncthreads();

    // ---- phase 2: edge loop over this block's half-segment ----
    const u32 beg = offs[b], end = offs[b + 1];
    const u32 len = end - beg;
    const u32 h0 = (len + 1) >> 1;
    const u32 hb = beg + ((blockIdx.x & 1) ? h0 : 0);
    const u32 he = (blockIdx.x & 1) ? end : beg + h0;
    const float* __restrict__ Wc = W1 + 16 * 32;   // col rows 16..23
    const float* __restrict__ W24 = W1 + 24 * 32;  // eprev row
    const float* __restrict__ W25 = W1 + 25 * 32;  // skip row
    float lsum = 0.0f;
    for (u32 i = hb + t; i < he; i += 512) {
        const uint4 e4 = einfo[i];
        const float attr = __uint_as_float(e4.w);
        float epv;
        if constexpr (FIRST) epv = attr;
        else epv = eprev[i];
        const u32 rl = e4.x & (NB_SIZE - 1);
        const int abase = rl * 32;
        const int asw_ = (rl & 7) << 2;
        float4 av[8];
#pragma unroll
        for (int q = 0; q < 8; ++q)
            av[q] = *(const float4*)&asw[abase + ((q * 4) ^ asw_)];
        const float4 xc0 = xf[2 * (size_t)e4.y];
        const float4 xc1 = xf[2 * (size_t)e4.y + 1];
        const float cx[8] = {xc0.x, xc0.y, xc0.z, xc0.w,
                             xc1.x, xc1.y, xc1.z, xc1.w};
        float hr[32];
#pragma unroll
        for (int q = 0; q < 8; ++q) {
            hr[4 * q + 0] = av[q].x; hr[4 * q + 1] = av[q].y;
            hr[4 * q + 2] = av[q].z; hr[4 * q + 3] = av[q].w;
        }
#pragma unroll
        for (int k = 0; k < 8; ++k) {
            const float v = cx[k];
#pragma unroll
            for (int j = 0; j < 32; ++j) hr[j] = fmaf(v, Wc[k * 32 + j], hr[j]);
        }
#pragma unroll
        for (int j = 0; j < 32; ++j) hr[j] = fmaf(epv, W24[j], hr[j]);
        if constexpr (SKIP) {
#pragma unroll
            for (int j = 0; j < 32; ++j) hr[j] = fmaf(attr, W25[j], hr[j]);
        }
        float out = b2[0];
#pragma unroll
        for (int j = 0; j < 32; ++j)
            out = fmaf(fmaxf(hr[j], 0.0f), W2[j], out);
        if constexpr (STORE) e_out[i] = out;
        if constexpr (VALS)
            vals_out[e4.z] = (e4.x == e4.y) ? expf(out) : out;
        if constexpr (GAGG) lsum += out;
    }
    if constexpr (GAGG) {
        __syncthreads();  // all waves done reading asw
        const float s = wave_sum(lsum);
        if ((t & 63) == 0) asw[t >> 6] = s;
        __syncthreads();
        if (t == 0) {
            float tot = 0.0f;
#pragma unroll
            for (int w = 0; w < 8; ++w) tot += asw[w];
            atomicAdd(&ebins[blockIdx.x & 63], tot);
        }
    }
}

// ------- fused aggregation + node MLP: one block owns one bucket -------

template <bool COUNT, bool STORE_N>
__global__ __launch_bounds__(1024) void aggnode_kernel(
    const float* __restrict__ ep,      // permuted edge embeddings
    const uint4* __restrict__ einfo,   // packed records (row in .x)
    const u32* __restrict__ offs,
    const float4* __restrict__ xf,  // node features: x (lower) or l_n (upper)
    float* __restrict__ cntf,       // per-node degree (write if COUNT)
    const float* __restrict__ g,    // gslot[j] (materialized)
    const float* __restrict__ nW1, const float* __restrict__ nb1,
    const float* __restrict__ nW2, const float* __restrict__ nb2,
    float* __restrict__ n_out,  // l_n (8N) if STORE_N
    float* __restrict__ nbins,  // 64 x 16 n-mean partial bins
    int N) {
    __shared__ float sbin[NB_SIZE];
    __shared__ float cbin[NB_SIZE];
    __shared__ float biasN[32];
    __shared__ float npart[8][8];
    const int t = threadIdx.x;
    if (t < NB_SIZE) {
        sbin[t] = 0.0f;
        if constexpr (COUNT) cbin[t] = 0.0f;
    }
    if (t >= NB_SIZE && t < NB_SIZE + 32) {
        const int j = t - NB_SIZE;
        float v = nb1[j];
#pragma unroll
        for (int k = 0; k < 8; ++k) v = fmaf(g[k], nW1[k * 32 + j], v);
        biasN[j] = v;
    }
    __syncthreads();
    const int b = blockIdx.x;
    const u32 beg = offs[b], end = offs[b + 1];
    for (u32 i = beg + t; i < end; i += 1024) {
        const float v = ep[i];
        const u32 rl = einfo[i].x & (NB_SIZE - 1);
        atomicAdd(&sbin[rl], v);
        if constexpr (COUNT) atomicAdd(&cbin[rl], 1.0f);
    }
    __syncthreads();

    const int n0 = b << NB_SHIFT;
    float o[8];
    const bool active = (t < NB_SIZE) && (n0 + t < N);
    if (t < NB_SIZE) {
        const int n = n0 + t;
        const int idx = active ? n : (N - 1);
        float cntv;
        if constexpr (COUNT) {
            cntv = cbin[t];
            if (active) cntf[n] = cntv;
        } else {
            cntv = cntf[idx];
        }
        const float agg = sbin[t] / fmaxf(cntv, 1.0f);
        const float4 x0 = xf[2 * idx], x1 = xf[2 * idx + 1];
        float in[9] = {x0.x, x0.y, x0.z, x0.w, x1.x, x1.y, x1.z, x1.w, agg};
        float h[32];
#pragma unroll
        for (int j = 0; j < 8; ++j) {
            const float4 bb = reinterpret_cast<const float4*>(biasN)[j];
            h[4 * j + 0] = bb.x; h[4 * j + 1] = bb.y;
            h[4 * j + 2] = bb.z; h[4 * j + 3] = bb.w;
        }
        const float* __restrict__ Wk = nW1 + 8 * 32;
#pragma unroll
        for (int k = 0; k < 9; ++k) {
            const float v = in[k];
#pragma unroll
            for (int j = 0; j < 32; ++j) h[j] = fmaf(v, Wk[k * 32 + j], h[j]);
        }
#pragma unroll
        for (int q = 0; q < 8; ++q) o[q] = nb2[q];
#pragma unroll
        for (int j = 0; j < 32; ++j) {
            const float hv = fmaxf(h[j], 0.0f);
#pragma unroll
            for (int q = 0; q < 8; ++q) o[q] = fmaf(hv, nW2[j * 8 + q], o[q]);
        }
        if constexpr (STORE_N) {
            if (active) {
                reinterpret_cast<float4*>(n_out)[2 * n] =
                    make_float4(o[0], o[1], o[2], o[3]);
                reinterpret_cast<float4*>(n_out)[2 * n + 1] =
                    make_float4(o[4], o[5], o[6], o[7]);
            }
        }
#pragma unroll
        for (int q = 0; q < 8; ++q) {
            const float s = wave_sum(active ? o[q] : 0.0f);
            if ((t & 63) == 0) npart[t >> 6][q] = s;
        }
    }
    __syncthreads();
    if (t < 8) {
        float a = 0.0f;
#pragma unroll
        for (int w = 0; w < 8; ++w) a += npart[w][t];
        atomicAdd(&nbins[(b & 63) * 16 + t], a);
    }
}

extern "C" void kernel_launch(void* const* d_in, const int* in_sizes, int n_in,
                              void* d_out, int out_size, void* d_ws,
                              size_t ws_size, hipStream_t stream) {
    const float* x = (const float*)d_in[0];
    const int* l_ei = (const int*)d_in[1];
    const int* u_ei = (const int*)d_in[2];
    const float* l_attr = (const float*)d_in[3];
    const float* u_attr = (const float*)d_in[4];
    const float* eW1 = (const float*)d_in[5];
    const float* eb1 = (const float*)d_in[6];
    const float* eW2 = (const float*)d_in[7];
    const float* eb2 = (const float*)d_in[8];
    const float* nW1 = (const float*)d_in[9];
    const float* nb1 = (const float*)d_in[10];
    const float* nW2 = (const float*)d_in[11];
    const float* nb2 = (const float*)d_in[12];
    const float* gW1 = (const float*)d_in[13];
    const float* gb1 = (const float*)d_in[14];
    const float* gW2 = (const float*)d_in[15];
    const float* gb2 = (const float*)d_in[16];

    const int E = in_sizes[3];      // 1,100,000
    const int N = in_sizes[0] / 8;  // 100,000
    const int B = (N + NB_SIZE - 1) >> NB_SHIFT;  // 196 buckets
    const int Ep = (E + 3) & ~3;    // float4-safe stride for emb arrays

    // workspace layout. einfo first (16B-aligned at base).
    uint4* einfo = (uint4*)d_ws;                   // 2E packed records
    float* l_e = (float*)(einfo + (size_t)2 * E);  // Ep
    float* u_e = l_e + Ep;                         // Ep
    float* l_n = u_e + Ep;                         // 8N (float4-aligned)
    float* cnt_l = l_n + (size_t)8 * N;            // N
    float* cnt_u = cnt_l + N;                      // N
    float* gslot = cnt_u + N;                      // 7 x 8
    u32* hist = (u32*)(gslot + 56);                // 2B
    float* dyn_all = (float*)(hist + 2 * B);       // 5 * RSTRIDE
    u32* offs = (u32*)(dyn_all + 5 * RSTRIDE);     // 2(B+1)
    u32* cur = offs + 2 * (B + 1);                 // 2B

    const int* lr = l_ei;
    const int* lc = l_ei + E;
    const int* ur = u_ei;
    const int* uc = u_ei + E;
    const int sg = (E + SCHUNK - 1) / SCHUNK;
    const float invE = 1.0f / (float)E;
    float* outL = (float*)d_out;
    float* outU = outL + E;
    const u32* offs_l = offs;
    const u32* offs_u = offs + (B + 1);

    // one memset: gslots + hist + all 5 bin regions
    hipMemsetAsync(gslot, 0, (size_t)(56 + 2 * B + 5 * RSTRIDE) * sizeof(float),
                   stream);
    hist_kernel<<<dim3(128, 2), 256, 0, stream>>>(lr, ur, hist, E, B);
    scan_kernel<<<1, 256, 0, stream>>>(hist, offs, cur, B);
    scatter_kernel<<<dim3(sg, 2), 256, 0, stream>>>(lr, lc, ur, uc, l_attr,
                                                    u_attr, cur, einfo, E, B);

    // weight-slice per GraphNet j: lower i -> i, upper i -> 3+i
    const size_t wsl[6] = {0, 3, 1, 4, 2, 5};

    for (int j = 0; j < 6; ++j) {
        const bool lower = !(j & 1);
        const size_t sl = wsl[j];
        float* ebins = dyn_all + (size_t)(j <= 4 ? j : 4) * RSTRIDE;
        float* nbins = ebins + 64;
        const float* pe = (j >= 1) ? dyn_all + (size_t)(j - 1) * RSTRIDE : nullptr;
        const float* pn = (j >= 1) ? pe + 64 : nullptr;
        const size_t psl = (j >= 1) ? wsl[j - 1] : 0;
        const float4* exf = (const float4*)(lower ? x : l_n);
        const uint4* einfo_t = einfo + (size_t)(lower ? 0 : 1) * E;
        const u32* eoffs = lower ? offs_l : offs_u;
        const float* eprev = lower ? l_e : u_e;  // unused when FIRST
        float* e_out = lower ? l_e : u_e;
        const float* gprev = gslot + (size_t)(j >= 1 ? j - 1 : 0) * 8;
        float* gout = gslot + (size_t)j * 8;

#define EDGE_ARGS                                                             \
    einfo_t, exf, eoffs, eprev, eW1 + sl * 832, eb1 + sl * 32,                \
        eW2 + sl * 32, eb2 + sl, gprev, gout, pe, pn, gW1 + psl * 544,        \
        gb1 + psl * 32, gW2 + psl * 256, gb2 + psl * 8, ebins, e_out,         \
        (j == 4) ? outL : outU, N, invE

        switch (j) {  // SKIP, FIRST, GAGG, VALS, STORE, GCOMP
            case 0: edge_kernel<false, true, true, false, true, false>
                        <<<2 * B, 512, 0, stream>>>(EDGE_ARGS); break;
            case 1: edge_kernel<false, true, true, false, true, true>
                        <<<2 * B, 512, 0, stream>>>(EDGE_ARGS); break;
            case 2: edge_kernel<true, false, true, false, true, true>
                        <<<2 * B, 512, 0, stream>>>(EDGE_ARGS); break;
            case 3: edge_kernel<false, false, true, false, true, true>
                        <<<2 * B, 512, 0, stream>>>(EDGE_ARGS); break;
            case 4: edge_kernel<true, false, true, true, true, true>
                        <<<2 * B, 512, 0, stream>>>(EDGE_ARGS); break;
            case 5: edge_kernel<false, false, false, true, false, true>
                        <<<2 * B, 512, 0, stream>>>(EDGE_ARGS); break;
        }
#undef EDGE_ARGS

        if (j == 5) break;  // final upper GraphNet: edge output only

        float* cntf = lower ? cnt_l : cnt_u;
        const float4* nxf = (const float4*)(lower ? x : l_n);

#define AGG_ARGS                                                              \
    e_out, einfo_t, eoffs, nxf, cntf, gslot + (size_t)j * 8, nW1 + sl * 544,  \
        nb1 + sl * 32, nW2 + sl * 256, nb2 + sl * 8, l_n, nbins, N

        switch (j) {  // COUNT, STORE_N
            case 0: aggnode_kernel<true, true>
                        <<<B, 1024, 0, stream>>>(AGG_ARGS); break;
            case 1: aggnode_kernel<true, false>
                        <<<B, 1024, 0, stream>>>(AGG_ARGS); break;
            case 2: aggnode_kernel<false, true>
                        <<<B, 1024, 0, stream>>>(AGG_ARGS); break;
            case 3: aggnode_kernel<false, false>
                        <<<B, 1024, 0, stream>>>(AGG_ARGS); break;
            case 4: aggnode_kernel<false, true>
                        <<<B, 1024, 0, stream>>>(AGG_ARGS); break;
        }
#undef AGG_ARGS
    }
}

// Round 4
// 549.519 us; speedup vs baseline: 1.3485x; 1.1036x over previous
//
#include <hip/hip_runtime.h>

// NeuralIF GraphNet: 3 layers x (lower GraphNet, upper GraphNet).
// R1: bucketed edge lists + LDS-bin aggregation.
// R7: one-edge-per-thread edge kernel. 548us.
// R8 FAILED: global A/B tables, original edge order -> 139MB L3 gather.
// R9: bucket-permuted order; 4-array scatter write-amp (160MB) -> 120us.
// R10: packed uint4 scatter (fixed); but per-bucket edge blocks w/ 64KB LDS
//      window -> occupancy 20% (2 blocks/CU cap + 392-block imbalance tail),
//      62us/dispatch. LDS window recompute also +20% VALU.
// R11 (this round): flat one-edge-per-thread edge kernel again, NO LDS window.
//  - NB_SHIFT=8: 256-node buckets -> 32KB A-window = L1-sized; Atab gathers in
//    bucket-permuted order stay L1/L2-hot.
//  - nodew_kernel folds b1 + g.W1[0:8] into Atab rows and computes g itself
//    (redundant per block; block0 writes gslot[j]) -> edge kernel has zero
//    setup, ~390 VALU/edge, tiny LDS, full occupancy.
//  - XCD-chunked blockIdx swizzle (padded grid) -> each XCD L2 touches a
//    contiguous ~1.6MB Atab slice instead of re-fetching all 12.8MB.
//  - B=391 now: 512-thread scan, 512-bin hist/scatter, 512-thr aggnode.

typedef unsigned int u32;

#define NB_SHIFT 8
#define NB_SIZE 256
#define RSTRIDE 1104  // per-GraphNet region: ebins[64] nbins[64*16] pad

__device__ __forceinline__ float wave_sum(float v) {
#pragma unroll
    for (int off = 32; off > 0; off >>= 1) v += __shfl_down(v, off, 64);
    return v;
}

// ---------------- bucketed-list build (once per call) ----------------

__global__ __launch_bounds__(512) void hist_kernel(
    const int* __restrict__ lr, const int* __restrict__ ur,
    u32* __restrict__ hist, int E, int B) {
    __shared__ u32 h[512];
    const int t = threadIdx.x;
    if (t < B) h[t] = 0;
    __syncthreads();
    const int s = blockIdx.y;
    const int* rows = s ? ur : lr;
    for (int i = blockIdx.x * 512 + t; i < E; i += gridDim.x * 512)
        atomicAdd(&h[rows[i] >> NB_SHIFT], 1u);
    __syncthreads();
    if (t < B && h[t]) atomicAdd(&hist[s * B + t], h[t]);
}

// parallel exclusive scan of both segments (B <= 512), one block
__global__ __launch_bounds__(512) void scan_kernel(
    const u32* __restrict__ hist, u32* __restrict__ offs,
    u32* __restrict__ cur, int B) {
    __shared__ u32 sh[512];
    const int t = threadIdx.x;
    for (int s = 0; s < 2; ++s) {
        const u32 v = (t < B) ? hist[s * B + t] : 0u;
        sh[t] = v;
        __syncthreads();
#pragma unroll
        for (int off = 1; off < 512; off <<= 1) {
            const u32 add = (t >= off) ? sh[t - off] : 0u;
            __syncthreads();
            sh[t] += add;
            __syncthreads();
        }
        const u32 exc = sh[t] - v;
        if (t < B) {
            offs[s * (B + 1) + t] = exc;
            cur[s * B + t] = exc;
        }
        if (t == 511) offs[s * (B + 1) + B] = sh[511];
        __syncthreads();
    }
}

// scatter: build packed permuted edge records {row, col, eid, attr}
#define SCHUNK 4096
__global__ __launch_bounds__(512) void scatter_kernel(
    const int* __restrict__ lr, const int* __restrict__ lc,
    const int* __restrict__ ur, const int* __restrict__ uc,
    const float* __restrict__ la, const float* __restrict__ ua,
    u32* __restrict__ cur, uint4* __restrict__ einfo, int E, int B) {
    __shared__ u32 lcnt[512], lbase[512];
    const int t = threadIdx.x;
    const int s = blockIdx.y;
    const int* rows = s ? ur : lr;
    const int* cols = s ? uc : lc;
    const float* attr = s ? ua : la;
    uint4* my = einfo + (size_t)s * E;
    if (t < B) lcnt[t] = 0;
    __syncthreads();
    const int base_e = blockIdx.x * SCHUNK;
#pragma unroll
    for (int k = 0; k < SCHUNK / 512; ++k) {
        const int e = base_e + k * 512 + t;
        if (e < E) atomicAdd(&lcnt[rows[e] >> NB_SHIFT], 1u);
    }
    __syncthreads();
    if (t < B) {
        const u32 c = lcnt[t];
        lbase[t] = c ? atomicAdd(&cur[s * B + t], c) : 0u;
        lcnt[t] = 0;
    }
    __syncthreads();
#pragma unroll
    for (int k = 0; k < SCHUNK / 512; ++k) {
        const int e = base_e + k * 512 + t;
        if (e < E) {
            const int r = rows[e];
            const int b = r >> NB_SHIFT;
            const u32 pos = lbase[b] + atomicAdd(&lcnt[b], 1u);
            my[pos] = make_uint4((u32)r, (u32)cols[e], (u32)e,
                                 __float_as_uint(attr[e]));
        }
    }
}

// -------- per-node A-table with g+bias fold (and the g-MLP itself) --------
// Atab[n][j] = b1[j] + sum_k g[k]*W1[k,j] + sum_k x[n,k]*W1[8+k,j]
// Every block redundantly computes g (tiny); block 0 materializes gslot[j].

template <bool GCOMP>
__global__ __launch_bounds__(256) void nodew_kernel(
    const float4* __restrict__ xf, const float* __restrict__ W1,
    const float* __restrict__ b1,
    const float* __restrict__ gprev,   // gslot[j-1] (or gslot[0]=0)
    float* __restrict__ gout,          // gslot[j] (GCOMP: block0 writes)
    const float* __restrict__ pebins,  // prev region e-mean bins (GCOMP)
    const float* __restrict__ pnbins,  // prev region n-mean bins (GCOMP)
    const float* __restrict__ gW1, const float* __restrict__ gb1,
    const float* __restrict__ gW2, const float* __restrict__ gb2,
    float4* __restrict__ Atab, int N, float inv_E) {
    __shared__ float gsh[8];
    const int t = threadIdx.x;
    if constexpr (GCOMP) {
        if (t < 64) {  // wave 0: g = gMLP(n_mean, e_mean, g_prev)
            float nb[8];
#pragma unroll
            for (int q = 0; q < 8; ++q) nb[q] = pnbins[t * 16 + q];
            const float eb = pebins[t];
            float gin[17];
#pragma unroll
            for (int q = 0; q < 8; ++q) {
                const float s = wave_sum(nb[q]);
                gin[q] = __shfl(s, 0, 64) / (float)N;
            }
            const float es = wave_sum(eb);
            gin[8] = __shfl(es, 0, 64) * inv_E;
#pragma unroll
            for (int k = 0; k < 8; ++k) gin[9 + k] = gprev[k];
            float hv = 0.0f;
            if (t < 32) {
                hv = gb1[t];
#pragma unroll
                for (int k = 0; k < 17; ++k)
                    hv = fmaf(gin[k], gW1[k * 32 + t], hv);
                hv = fmaxf(hv, 0.0f);
            }
#pragma unroll
            for (int q = 0; q < 8; ++q) {
                const float c = (t < 32) ? hv * gW2[t * 8 + q] : 0.0f;
                const float s = wave_sum(c);
                if (t == 0) {
                    const float gv = gb2[q] + s;
                    gsh[q] = gv;
                    if (blockIdx.x == 0) gout[q] = gv;
                }
            }
        }
    } else {
        if (t < 8) gsh[t] = gprev[t];  // zeros for GraphNet 0
    }
    __syncthreads();
    const int n = blockIdx.x * 256 + t;
    if (n >= N) return;
    float gr[8];
#pragma unroll
    for (int k = 0; k < 8; ++k) gr[k] = gsh[k];
    const float4 x0 = xf[2 * (size_t)n], x1 = xf[2 * (size_t)n + 1];
    const float xs[8] = {x0.x, x0.y, x0.z, x0.w, x1.x, x1.y, x1.z, x1.w};
    float a[32];
#pragma unroll
    for (int j = 0; j < 32; ++j) {
        float v = b1[j];
#pragma unroll
        for (int k = 0; k < 8; ++k) v = fmaf(gr[k], W1[k * 32 + j], v);
        a[j] = v;
    }
    const float* __restrict__ WA = W1 + 8 * 32;
#pragma unroll
    for (int k = 0; k < 8; ++k) {
        const float v = xs[k];
#pragma unroll
        for (int j = 0; j < 32; ++j) a[j] = fmaf(v, WA[k * 32 + j], a[j]);
    }
    float4* An = Atab + 8 * (size_t)n;
#pragma unroll
    for (int q = 0; q < 8; ++q)
        An[q] = make_float4(a[4 * q], a[4 * q + 1], a[4 * q + 2], a[4 * q + 3]);
}

// ---------------- edge MLP: flat grid, one edge per thread ----------------
// Bucket-permuted order keeps Atab row-gathers inside a 32KB (L1-sized)
// window. XCD-chunked swizzle keeps each XCD's L2 on a contiguous Atab slice.

template <bool SKIP, bool FIRST, bool GAGG, bool VALS, bool STORE>
__global__ __launch_bounds__(256) void edge_kernel(
    const uint4* __restrict__ einfo,   // packed permuted records
    const float4* __restrict__ Atab,   // folded per-node partials
    const float4* __restrict__ xf,     // current node features (x or l_n)
    const float* __restrict__ eprev,   // prev edge emb (permuted), !FIRST
    const float* __restrict__ W1,      // 26x32 slice (row-major k,j)
    const float* __restrict__ W2,      // 32
    const float* __restrict__ b2,      // 1
    float* __restrict__ ebins,         // this region's e-mean bins (GAGG)
    float* __restrict__ e_out,         // edge emb store (permuted, STORE)
    float* __restrict__ vals_out,      // final output segment (VALS)
    int E, int cpx) {
    __shared__ float wpart[4];
    const int t = threadIdx.x;
    const int lid = (blockIdx.x & 7) * cpx + (blockIdx.x >> 3);
    const int i0 = lid * 256;
    if (i0 >= E) return;  // padded-grid tail block
    const int i = i0 + t;
    const bool valid = i < E;
    const int idx = valid ? i : i0;

    const uint4 e4 = einfo[idx];
    const float attr = __uint_as_float(e4.w);
    float epv;
    if constexpr (FIRST) epv = attr;
    else epv = eprev[idx];
    // A-row gather (8x16B inside this bucket's 32KB window)
    const float4* __restrict__ Ar = Atab + 8 * (size_t)e4.x;
    float h[32];
#pragma unroll
    for (int q = 0; q < 8; ++q) {
        const float4 av = Ar[q];
        h[4 * q + 0] = av.x; h[4 * q + 1] = av.y;
        h[4 * q + 2] = av.z; h[4 * q + 3] = av.w;
    }
    // col features (32B gather, L2-resident table)
    const float4 xc0 = xf[2 * (size_t)e4.y], xc1 = xf[2 * (size_t)e4.y + 1];
    const float cx[8] = {xc0.x, xc0.y, xc0.z, xc0.w,
                         xc1.x, xc1.y, xc1.z, xc1.w};
    const float* __restrict__ Wc = W1 + 16 * 32;  // col rows 16..23
#pragma unroll
    for (int k = 0; k < 8; ++k) {
        const float v = cx[k];
#pragma unroll
        for (int j = 0; j < 32; ++j) h[j] = fmaf(v, Wc[k * 32 + j], h[j]);
    }
    const float* __restrict__ W24 = W1 + 24 * 32;
#pragma unroll
    for (int j = 0; j < 32; ++j) h[j] = fmaf(epv, W24[j], h[j]);
    if constexpr (SKIP) {
        const float* __restrict__ W25 = W1 + 25 * 32;
#pragma unroll
        for (int j = 0; j < 32; ++j) h[j] = fmaf(attr, W25[j], h[j]);
    }
    float out = b2[0];
#pragma unroll
    for (int j = 0; j < 32; ++j) out = fmaf(fmaxf(h[j], 0.0f), W2[j], out);

    if (valid) {
        if constexpr (STORE) e_out[i] = out;
        if constexpr (VALS)
            vals_out[e4.z] = (e4.x == e4.y) ? expf(out) : out;
    }
    if constexpr (GAGG) {
        const float s = wave_sum(valid ? out : 0.0f);
        if ((t & 63) == 0) wpart[t >> 6] = s;
        __syncthreads();
        if (t == 0)
            atomicAdd(&ebins[lid & 63],
                      wpart[0] + wpart[1] + wpart[2] + wpart[3]);
    }
}

// ------- fused aggregation + node MLP: one block owns one bucket -------

template <bool COUNT, bool STORE_N>
__global__ __launch_bounds__(512) void aggnode_kernel(
    const float* __restrict__ ep,      // permuted edge embeddings
    const uint4* __restrict__ einfo,   // packed records (row in .x)
    const u32* __restrict__ offs,
    const float4* __restrict__ xf,  // node features: x (lower) or l_n (upper)
    float* __restrict__ cntf,       // per-node degree (write if COUNT)
    const float* __restrict__ g,    // gslot[j] (materialized)
    const float* __restrict__ nW1, const float* __restrict__ nb1,
    const float* __restrict__ nW2, const float* __restrict__ nb2,
    float* __restrict__ n_out,  // l_n (8N) if STORE_N
    float* __restrict__ nbins,  // 64 x 16 n-mean partial bins
    int N) {
    __shared__ float sbin[NB_SIZE];
    __shared__ float cbin[NB_SIZE];
    __shared__ float biasN[32];
    __shared__ float npart[4][8];
    const int t = threadIdx.x;
    if (t < NB_SIZE) {
        sbin[t] = 0.0f;
        if constexpr (COUNT) cbin[t] = 0.0f;
    }
    if (t >= NB_SIZE && t < NB_SIZE + 32) {
        const int j = t - NB_SIZE;
        float v = nb1[j];
#pragma unroll
        for (int k = 0; k < 8; ++k) v = fmaf(g[k], nW1[k * 32 + j], v);
        biasN[j] = v;
    }
    __syncthreads();
    const int b = blockIdx.x;
    const u32 beg = offs[b], end = offs[b + 1];
    for (u32 i = beg + t; i < end; i += 512) {
        const float v = ep[i];
        const u32 rl = einfo[i].x & (NB_SIZE - 1);
        atomicAdd(&sbin[rl], v);
        if constexpr (COUNT) atomicAdd(&cbin[rl], 1.0f);
    }
    __syncthreads();

    const int n0 = b << NB_SHIFT;
    float o[8];
    const bool active = (t < NB_SIZE) && (n0 + t < N);
    if (t < NB_SIZE) {
        const int n = n0 + t;
        const int idx = active ? n : (N - 1);
        float cntv;
        if constexpr (COUNT) {
            cntv = cbin[t];
            if (active) cntf[n] = cntv;
        } else {
            cntv = cntf[idx];
        }
        const float agg = sbin[t] / fmaxf(cntv, 1.0f);
        const float4 x0 = xf[2 * idx], x1 = xf[2 * idx + 1];
        float in[9] = {x0.x, x0.y, x0.z, x0.w, x1.x, x1.y, x1.z, x1.w, agg};
        float h[32];
#pragma unroll
        for (int j = 0; j < 8; ++j) {
            const float4 bb = reinterpret_cast<const float4*>(biasN)[j];
            h[4 * j + 0] = bb.x; h[4 * j + 1] = bb.y;
            h[4 * j + 2] = bb.z; h[4 * j + 3] = bb.w;
        }
        const float* __restrict__ Wk = nW1 + 8 * 32;
#pragma unroll
        for (int k = 0; k < 9; ++k) {
            const float v = in[k];
#pragma unroll
            for (int j = 0; j < 32; ++j) h[j] = fmaf(v, Wk[k * 32 + j], h[j]);
        }
#pragma unroll
        for (int q = 0; q < 8; ++q) o[q] = nb2[q];
#pragma unroll
        for (int j = 0; j < 32; ++j) {
            const float hv = fmaxf(h[j], 0.0f);
#pragma unroll
            for (int q = 0; q < 8; ++q) o[q] = fmaf(hv, nW2[j * 8 + q], o[q]);
        }
        if constexpr (STORE_N) {
            if (active) {
                reinterpret_cast<float4*>(n_out)[2 * n] =
                    make_float4(o[0], o[1], o[2], o[3]);
                reinterpret_cast<float4*>(n_out)[2 * n + 1] =
                    make_float4(o[4], o[5], o[6], o[7]);
            }
        }
#pragma unroll
        for (int q = 0; q < 8; ++q) {
            const float s = wave_sum(active ? o[q] : 0.0f);
            if ((t & 63) == 0) npart[t >> 6][q] = s;
        }
    }
    __syncthreads();
    if (t < 8) {
        float a = 0.0f;
#pragma unroll
        for (int w = 0; w < 4; ++w) a += npart[w][t];
        atomicAdd(&nbins[(b & 63) * 16 + t], a);
    }
}

extern "C" void kernel_launch(void* const* d_in, const int* in_sizes, int n_in,
                              void* d_out, int out_size, void* d_ws,
                              size_t ws_size, hipStream_t stream) {
    const float* x = (const float*)d_in[0];
    const int* l_ei = (const int*)d_in[1];
    const int* u_ei = (const int*)d_in[2];
    const float* l_attr = (const float*)d_in[3];
    const float* u_attr = (const float*)d_in[4];
    const float* eW1 = (const float*)d_in[5];
    const float* eb1 = (const float*)d_in[6];
    const float* eW2 = (const float*)d_in[7];
    const float* eb2 = (const float*)d_in[8];
    const float* nW1 = (const float*)d_in[9];
    const float* nb1 = (const float*)d_in[10];
    const float* nW2 = (const float*)d_in[11];
    const float* nb2 = (const float*)d_in[12];
    const float* gW1 = (const float*)d_in[13];
    const float* gb1 = (const float*)d_in[14];
    const float* gW2 = (const float*)d_in[15];
    const float* gb2 = (const float*)d_in[16];

    const int E = in_sizes[3];      // 1,100,000
    const int N = in_sizes[0] / 8;  // 100,000
    const int B = (N + NB_SIZE - 1) >> NB_SHIFT;  // 391 buckets
    const int Ep = (E + 3) & ~3;    // float4-safe stride for emb arrays

    // workspace layout. einfo first (16B-aligned at base).
    uint4* einfo = (uint4*)d_ws;                   // 2E packed records
    float* Atab = (float*)(einfo + (size_t)2 * E); // 32N (folded partials)
    float* l_e = Atab + (size_t)32 * N;            // Ep
    float* u_e = l_e + Ep;                         // Ep
    float* l_n = u_e + Ep;                         // 8N (float4-aligned)
    float* cnt_l = l_n + (size_t)8 * N;            // N
    float* cnt_u = cnt_l + N;                      // N
    float* gslot = cnt_u + N;                      // 7 x 8
    u32* hist = (u32*)(gslot + 56);                // 2B
    float* dyn_all = (float*)(hist + 2 * B);       // 5 * RSTRIDE
    u32* offs = (u32*)(dyn_all + 5 * RSTRIDE);     // 2(B+1)
    u32* cur = offs + 2 * (B + 1);                 // 2B

    const int* lr = l_ei;
    const int* lc = l_ei + E;
    const int* ur = u_ei;
    const int* uc = u_ei + E;
    const int sg = (E + SCHUNK - 1) / SCHUNK;
    const int ng = (N + 255) / 256;
    const int eg = (E + 255) / 256;
    const int nwg8 = (eg + 7) & ~7;  // padded grid, %8 == 0 (bijective swz)
    const int cpx = nwg8 >> 3;
    const float invE = 1.0f / (float)E;
    float* outL = (float*)d_out;
    float* outU = outL + E;
    const u32* offs_l = offs;
    const u32* offs_u = offs + (B + 1);

    // one memset: gslots + hist + all 5 bin regions
    hipMemsetAsync(gslot, 0, (size_t)(56 + 2 * B + 5 * RSTRIDE) * sizeof(float),
                   stream);
    hist_kernel<<<dim3(64, 2), 512, 0, stream>>>(lr, ur, hist, E, B);
    scan_kernel<<<1, 512, 0, stream>>>(hist, offs, cur, B);
    scatter_kernel<<<dim3(sg, 2), 512, 0, stream>>>(lr, lc, ur, uc, l_attr,
                                                    u_attr, cur, einfo, E, B);

    // weight-slice per GraphNet j: lower i -> i, upper i -> 3+i
    const size_t wsl[6] = {0, 3, 1, 4, 2, 5};

    for (int j = 0; j < 6; ++j) {
        const bool lower = !(j & 1);
        const size_t sl = wsl[j];
        float* ebins = dyn_all + (size_t)(j <= 4 ? j : 4) * RSTRIDE;
        float* nbins = ebins + 64;
        const float* pe = (j >= 1) ? dyn_all + (size_t)(j - 1) * RSTRIDE : nullptr;
        const float* pn = (j >= 1) ? pe + 64 : nullptr;
        const size_t psl = (j >= 1) ? wsl[j - 1] : 0;
        const float4* exf = (const float4*)(lower ? x : l_n);
        const uint4* einfo_t = einfo + (size_t)(lower ? 0 : 1) * E;
        const u32* eoffs = lower ? offs_l : offs_u;
        const float* eprev = lower ? l_e : u_e;  // unused when FIRST
        float* e_out = lower ? l_e : u_e;
        const float* gprev = gslot + (size_t)(j >= 1 ? j - 1 : 0) * 8;
        float* gout = gslot + (size_t)j * 8;

        // folded per-node A-table (+ g-MLP; block0 materializes gslot[j])
        if (j == 0)
            nodew_kernel<false><<<ng, 256, 0, stream>>>(
                exf, eW1 + sl * 832, eb1 + sl * 32, gprev, gout, pe, pn,
                gW1, gb1, gW2, gb2, (float4*)Atab, N, invE);
        else
            nodew_kernel<true><<<ng, 256, 0, stream>>>(
                exf, eW1 + sl * 832, eb1 + sl * 32, gprev, gout, pe, pn,
                gW1 + psl * 544, gb1 + psl * 32, gW2 + psl * 256,
                gb2 + psl * 8, (float4*)Atab, N, invE);

#define EDGE_ARGS                                                             \
    einfo_t, (const float4*)Atab, exf, eprev, eW1 + sl * 832,                 \
        eW2 + sl * 32, eb2 + sl, ebins, e_out, (j == 4) ? outL : outU, E, cpx

        switch (j) {  // SKIP, FIRST, GAGG, VALS, STORE
            case 0: edge_kernel<false, true, true, false, true>
                        <<<nwg8, 256, 0, stream>>>(EDGE_ARGS); break;
            case 1: edge_kernel<false, true, true, false, true>
                        <<<nwg8, 256, 0, stream>>>(EDGE_ARGS); break;
            case 2: edge_kernel<true, false, true, false, true>
                        <<<nwg8, 256, 0, stream>>>(EDGE_ARGS); break;
            case 3: edge_kernel<false, false, true, false, true>
                        <<<nwg8, 256, 0, stream>>>(EDGE_ARGS); break;
            case 4: edge_kernel<true, false, true, true, true>
                        <<<nwg8, 256, 0, stream>>>(EDGE_ARGS); break;
            case 5: edge_kernel<false, false, false, true, false>
                        <<<nwg8, 256, 0, stream>>>(EDGE_ARGS); break;
        }
#undef EDGE_ARGS

        if (j == 5) break;  // final upper GraphNet: edge output only

        float* cntf = lower ? cnt_l : cnt_u;
        const float4* nxf = (const float4*)(lower ? x : l_n);

#define AGG_ARGS                                                              \
    e_out, einfo_t, eoffs, nxf, cntf, gslot + (size_t)j * 8, nW1 + sl * 544,  \
        nb1 + sl * 32, nW2 + sl * 256, nb2 + sl * 8, l_n, nbins, N

        switch (j) {  // COUNT, STORE_N
            case 0: aggnode_kernel<true, true>
                        <<<B, 512, 0, stream>>>(AGG_ARGS); break;
            case 1: aggnode_kernel<true, false>
                        <<<B, 512, 0, stream>>>(AGG_ARGS); break;
            case 2: aggnode_kernel<false, true>
                        <<<B, 512, 0, stream>>>(AGG_ARGS); break;
            case 3: aggnode_kernel<false, false>
                        <<<B, 512, 0, stream>>>(AGG_ARGS); break;
            case 4: aggnode_kernel<false, true>
                        <<<B, 512, 0, stream>>>(AGG_ARGS); break;
        }
#undef AGG_ARGS
    }
}